// Round 1
// baseline (1000.364 us; speedup 1.0000x reference)
//
#include <hip/hip_runtime.h>

#define SMP 64      // samples per block
#define NW 8        // waves per block
#define NT (NW*64)

constexpr float DTc  = 0.02f;
constexpr float ADc  = (2.0f/3.0f)*0.02f;   // alpha*DT
constexpr float EPSc = 1e-6f;

// S (per-sample small state) field offsets, stride 117 (odd -> conflict-free)
#define FQ   0
#define FQD  6
#define FT   12
#define FL   24   // 21 tril entries of L (also y accumulator, init = b3L)
#define FM   45   // 36 full symmetric M
#define FDV  81
#define FC1  87
#define FC2  93
#define FKQ  99   // qddot of stage 1 (k1)
#define FGT  105  // 12 V-grad wrt trig feats (atomic)
#define SSTR 117

#define HS 129    // odd stride for 128-vectors

__device__ __forceinline__ float softplusf(float z) {
    return fmaxf(z, 0.0f) + __logf(1.0f + __expf(-fabsf(z)));
}
__device__ __forceinline__ float sigmoidf_(float z) {
    float t = __expf(-fabsf(z));
    float r = 1.0f / (1.0f + t);
    return z >= 0.0f ? r : t * r;
}

__global__ void prep_kernel(const float* __restrict__ W1L, const float* __restrict__ W1V,
                            const float* __restrict__ W2V, float* __restrict__ ws) {
    int idx = blockIdx.x*256 + threadIdx.x;
    if (idx < 1536) {                       // W1LT[n*12+d] = W1L[d*128+n]
        int n = idx / 12, d = idx % 12;
        ws[idx] = W1L[d*128 + n];
    } else if (idx < 3072) {                // W1VT[m*12+d] = W1V[d*128+m]
        int j = idx - 1536;
        int m = j / 12, d = j % 12;
        ws[idx] = W1V[d*128 + m];
    } else if (idx < 19456) {               // W2VT[n*128+m] = W2V[m*128+n]
        int j = idx - 3072;
        int n = j / 128, m = j % 128;
        ws[idx] = W2V[m*128 + n];
    }
}

__launch_bounds__(NT)
__global__ void lnn_kernel(
    const float* __restrict__ o,   const float* __restrict__ aIn,
    const float* __restrict__ b1L, const float* __restrict__ W2L,
    const float* __restrict__ b2L, const float* __restrict__ W3L,
    const float* __restrict__ b3L,
    const float* __restrict__ b1V, const float* __restrict__ W2V,
    const float* __restrict__ b2V, const float* __restrict__ W3V,
    const float* __restrict__ W1LT, const float* __restrict__ W1VT,
    const float* __restrict__ W2VT,
    float* __restrict__ out)
{
    __shared__ float H1[SMP*HS];   // softplus(z1)  (MLP-L layer1)
    __shared__ float H2[SMP*HS];   // softplus(z2)  (MLP-L layer2)
    __shared__ float GH[SMP*HS];   // g2h = sigmoid(z2v)*W3V  (V backward seed)
    __shared__ float S[SMP*SSTR];

    const int tid  = threadIdx.x;
    const int lane = tid & 63;
    const int wv   = __builtin_amdgcn_readfirstlane(tid >> 6);
    const int gs   = blockIdx.x * SMP + lane;     // global sample of this lane
    float* Sl = &S[lane*SSTR];

    constexpr int TRW[21] = {0,1,1,2,2,2,3,3,3,3,4,4,4,4,4,5,5,5,5,5,5};
    constexpr int TCW[21] = {0,0,1,0,1,2,0,1,2,3,0,1,2,3,4,0,1,2,3,4,5};

    for (int stage = 0; stage < 2; ++stage) {
        // ---------------- P0: state init ----------------
        if (wv == 0) {
            if (stage == 0) {
                #pragma unroll
                for (int i = 0; i < 6; ++i) { Sl[FQ+i] = o[gs*18+i]; Sl[FQD+i] = o[gs*18+6+i]; }
            }
            #pragma unroll
            for (int i = 0; i < 6; ++i) {
                float q = Sl[FQ+i];
                Sl[FT+2*i]   = cosf(q);
                Sl[FT+2*i+1] = sinf(q);
            }
        } else if (wv == 1) {
            #pragma unroll
            for (int k = 0; k < 21; ++k) Sl[FL+k] = b3L[k];
        } else if (wv == 2) {
            #pragma unroll
            for (int i = 0; i < 6; ++i) { Sl[FC1+i] = 0.0f; Sl[FC2+i] = 0.0f; }
        } else if (wv == 3) {
            #pragma unroll
            for (int d = 0; d < 12; ++d) Sl[FGT+d] = 0.0f;
        }
        __syncthreads();

        float tt[12];
        #pragma unroll
        for (int d = 0; d < 12; ++d) tt[d] = Sl[FT+d];

        // ---------------- P1: layer-1 L (store h1) + layer-2 V (store g2h) ----------------
        {
            const int n0 = __builtin_amdgcn_readfirstlane(wv * 16);
            #pragma unroll
            for (int j = 0; j < 16; ++j) {
                int n = n0 + j;
                float z = b1L[n];
                #pragma unroll
                for (int d = 0; d < 12; ++d) z += tt[d] * W1LT[n*12+d];
                H1[lane*HS + n] = softplusf(z);
            }
            float acc[16];
            #pragma unroll
            for (int j = 0; j < 16; ++j) acc[j] = b2V[n0+j];
            for (int m = 0; m < 128; ++m) {
                float z1v = b1V[m];
                #pragma unroll
                for (int d = 0; d < 12; ++d) z1v += tt[d] * W1VT[m*12+d];
                float h1v = softplusf(z1v);
                const float* wr = &W2V[m*128 + n0];
                #pragma unroll
                for (int j = 0; j < 16; ++j) acc[j] += h1v * wr[j];
            }
            #pragma unroll
            for (int j = 0; j < 16; ++j) {
                int n = n0 + j;
                GH[lane*HS + n] = sigmoidf_(acc[j]) * W3V[n];
            }
        }
        __syncthreads();

        // ---------------- P2: layer-2 L (h2 + y partials) + V backward (gt partials) ----------------
        {
            const int n0 = __builtin_amdgcn_readfirstlane(wv * 16);
            float acc[16];
            #pragma unroll
            for (int j = 0; j < 16; ++j) acc[j] = b2L[n0+j];
            for (int m = 0; m < 128; ++m) {
                float hm = H1[lane*HS + m];
                const float* wr = &W2L[m*128 + n0];
                #pragma unroll
                for (int j = 0; j < 16; ++j) acc[j] += hm * wr[j];
            }
            float yp[21];
            #pragma unroll
            for (int k = 0; k < 21; ++k) yp[k] = 0.0f;
            #pragma unroll
            for (int j = 0; j < 16; ++j) {
                int n = n0 + j;
                float h2 = softplusf(acc[j]);
                H2[lane*HS + n] = h2;
                #pragma unroll
                for (int k = 0; k < 21; ++k) yp[k] += h2 * W3L[n*21 + k];
            }
            #pragma unroll
            for (int k = 0; k < 21; ++k) atomicAdd(&Sl[FL+k], yp[k]);

            // V backward: g1 = W2V . g2h (m-slice), fold to gt
            const int m0 = __builtin_amdgcn_readfirstlane(wv * 16);
            float ga[16];
            #pragma unroll
            for (int i = 0; i < 16; ++i) ga[i] = 0.0f;
            for (int n = 0; n < 128; ++n) {
                float gv = GH[lane*HS + n];
                const float* wr = &W2VT[n*128 + m0];
                #pragma unroll
                for (int i = 0; i < 16; ++i) ga[i] += gv * wr[i];
            }
            float gtp[12];
            #pragma unroll
            for (int d = 0; d < 12; ++d) gtp[d] = 0.0f;
            #pragma unroll
            for (int i = 0; i < 16; ++i) {
                int m = m0 + i;
                float z1v = b1V[m];
                #pragma unroll
                for (int d = 0; d < 12; ++d) z1v += tt[d] * W1VT[m*12+d];
                float g1h = ga[i] * sigmoidf_(z1v);
                #pragma unroll
                for (int d = 0; d < 12; ++d) gtp[d] += g1h * W1VT[m*12+d];
            }
            #pragma unroll
            for (int d = 0; d < 12; ++d) atomicAdd(&Sl[FGT+d], gtp[d]);
        }
        __syncthreads();

        // ---------------- P3: M = L L^T + eps I (waves 0-5, row each) ; dV/dq (wave 6) ----------------
        if (wv < 6) {
            int i = wv;
            for (int j = 0; j < 6; ++j) {
                float s = 0.0f;
                int mn = (i < j) ? i : j;
                for (int k = 0; k <= mn; ++k)
                    s += Sl[FL + (i*(i+1))/2 + k] * Sl[FL + (j*(j+1))/2 + k];
                if (i == j) s += EPSc;
                Sl[FM + i*6 + j] = s;
            }
        } else if (wv == 6) {
            #pragma unroll
            for (int i = 0; i < 6; ++i)
                Sl[FDV+i] = -tt[2*i+1]*Sl[FGT+2*i] + tt[2*i]*Sl[FGT+2*i+1];
        }
        __syncthreads();

        // ---------------- P4: 24 JVP quarter-units (dir, m-half, n-half), 3 per wave ----------------
        {
            float qd[6], u6[6], p6[6], r6[6];
            #pragma unroll
            for (int i = 0; i < 6; ++i) qd[i] = Sl[FQD+i];
            #pragma unroll
            for (int i = 0; i < 6; ++i) {
                float s = 0.0f;
                #pragma unroll
                for (int j = 0; j < 6; ++j) s += Sl[FM+i*6+j]*qd[j];
                u6[i] = s;                                  // u = M qd
            }
            #pragma unroll
            for (int i = 0; i < 6; ++i) { p6[i] = 0.0f; r6[i] = 0.0f; }
            #pragma unroll
            for (int t = 0; t < 21; ++t) {
                float Lv = Sl[FL+t];
                p6[TCW[t]] += Lv * qd[TRW[t]];              // p = L^T qd
                r6[TCW[t]] += Lv * u6[TRW[t]];              // r = L^T u
            }

            for (int uu = wv; uu < 24; uu += NW) {
                const int d     = __builtin_amdgcn_readfirstlane(uu >> 2);
                const int mbase = __builtin_amdgcn_readfirstlane(((uu >> 1) & 1) * 64);
                const int nbase = __builtin_amdgcn_readfirstlane((uu & 1) * 64);
                float tc = Sl[FT+2*d], ts = Sl[FT+2*d+1];
                float acc[64];
                #pragma unroll
                for (int n = 0; n < 64; ++n) acc[n] = 0.0f;
                for (int m = 0; m < 64; ++m) {
                    int mm = mbase + m;
                    float s1 = 1.0f - __expf(-H1[lane*HS + mm]);
                    float u1 = tc*W1LT[mm*12 + 2*d+1] - ts*W1LT[mm*12 + 2*d];
                    float dm = s1*u1;
                    const float* wr = &W2L[mm*128 + nbase];
                    #pragma unroll
                    for (int n = 0; n < 64; ++n) acc[n] += dm * wr[n];
                }
                float dy[21];
                #pragma unroll
                for (int k = 0; k < 21; ++k) dy[k] = 0.0f;
                #pragma unroll
                for (int n = 0; n < 64; ++n) {
                    int nn = nbase + n;
                    float d2 = (1.0f - __expf(-H2[lane*HS + nn])) * acc[n];
                    #pragma unroll
                    for (int k = 0; k < 21; ++k) dy[k] += d2 * W3L[nn*21 + k];
                }
                float a1[6],a2[6],a3[6],a4[6];
                #pragma unroll
                for (int i = 0; i < 6; ++i) { a1[i]=0.f; a2[i]=0.f; a3[i]=0.f; a4[i]=0.f; }
                #pragma unroll
                for (int t = 0; t < 21; ++t) {
                    float dv = dy[t];
                    a1[TRW[t]] += dv * p6[TCW[t]];          // dL . p
                    a2[TCW[t]] += dv * qd[TRW[t]];          // dL^T qd
                    a3[TRW[t]] += dv * r6[TCW[t]];          // dL . r
                    a4[TCW[t]] += dv * u6[TRW[t]];          // dL^T u
                }
                float w6[6], v6[6];
                #pragma unroll
                for (int i = 0; i < 6; ++i) { w6[i] = a1[i]; v6[i] = a3[i]; }
                #pragma unroll
                for (int t = 0; t < 21; ++t) {
                    float Lv = Sl[FL+t];
                    w6[TRW[t]] += Lv * a2[TCW[t]];          // w = dM qd
                    v6[TRW[t]] += Lv * a4[TCW[t]];          // v = dM u
                }
                float qdd = Sl[FQD + d];
                float uw = 0.0f;
                #pragma unroll
                for (int i = 0; i < 6; ++i) {
                    float mw = 0.0f;
                    #pragma unroll
                    for (int j = 0; j < 6; ++j) mw += Sl[FM+i*6+j]*w6[j];
                    atomicAdd(&Sl[FC1+i], qdd*(v6[i]+mw));  // c1 += qd_d * S_d qd
                    uw += u6[i]*w6[i];
                }
                atomicAdd(&Sl[FC2+d], 2.0f*uw);             // c2_d = qd^T S_d qd
            }
        }
        __syncthreads();

        // ---------------- P5: epilogue (wave 0): c, rhs, inv(tril(M)), qddot, RK update ----------------
        if (wv == 0) {
            float rhs[6];
            #pragma unroll
            for (int i = 0; i < 6; ++i) {
                float c = Sl[FC1+i] - 0.5f*Sl[FC2+i];
                rhs[i] = aIn[gs*6+i] - c - Sl[FDV+i];
            }
            float Mm[36];
            #pragma unroll
            for (int i = 0; i < 36; ++i) Mm[i] = Sl[FM+i];
            float Li[21];
            #pragma unroll
            for (int j = 0; j < 6; ++j) {
                float x[6];
                x[j] = 1.0f / Mm[j*6+j];
                #pragma unroll
                for (int i2 = j+1; i2 < 6; ++i2) {
                    float s = 0.0f;
                    #pragma unroll
                    for (int k = j; k < i2; ++k) s += Mm[i2*6+k]*x[k];
                    x[i2] = -s / Mm[i2*6+i2];
                }
                #pragma unroll
                for (int i2 = j; i2 < 6; ++i2) Li[(i2*(i2+1))/2 + j] = x[i2];
            }
            float y1[6];
            #pragma unroll
            for (int i = 0; i < 6; ++i) {
                float s = 0.0f;
                #pragma unroll
                for (int j = 0; j <= i; ++j) s += Li[(i*(i+1))/2+j]*rhs[j];
                y1[i] = s;
            }
            float qdd2[6];
            #pragma unroll
            for (int i = 0; i < 6; ++i) {
                float s = 0.0f;
                #pragma unroll
                for (int k = i; k < 6; ++k) s += Li[(k*(k+1))/2+i]*y1[k];
                qdd2[i] = s;
            }
            if (stage == 0) {
                #pragma unroll
                for (int i = 0; i < 6; ++i) Sl[FKQ+i] = qdd2[i];
                #pragma unroll
                for (int i = 0; i < 6; ++i) Sl[FQ+i] += ADc*Sl[FQD+i];   // uses old qd
                #pragma unroll
                for (int i = 0; i < 6; ++i) Sl[FQD+i] += ADc*qdd2[i];
            } else {
                #pragma unroll
                for (int i = 0; i < 6; ++i) {
                    float q0 = o[gs*18+i], qd0 = o[gs*18+6+i];
                    out[gs*18+i]    = q0  + DTc*(0.25f*qd0      + 0.75f*Sl[FQD+i]);
                    out[gs*18+6+i]  = qd0 + DTc*(0.25f*Sl[FKQ+i] + 0.75f*qdd2[i]);
                    out[gs*18+12+i] = o[gs*18+12+i];
                }
            }
        }
        __syncthreads();
    }
}

extern "C" void kernel_launch(void* const* d_in, const int* in_sizes, int n_in,
                              void* d_out, int out_size, void* d_ws, size_t ws_size,
                              hipStream_t stream) {
    const float* o   = (const float*)d_in[0];
    const float* a   = (const float*)d_in[1];
    const float* W1L = (const float*)d_in[2];
    const float* b1L = (const float*)d_in[3];
    const float* W2L = (const float*)d_in[4];
    const float* b2L = (const float*)d_in[5];
    const float* W3L = (const float*)d_in[6];
    const float* b3L = (const float*)d_in[7];
    const float* W1V = (const float*)d_in[8];
    const float* b1V = (const float*)d_in[9];
    const float* W2V = (const float*)d_in[10];
    const float* b2V = (const float*)d_in[11];
    const float* W3V = (const float*)d_in[12];
    float* ws   = (float*)d_ws;
    float* outp = (float*)d_out;

    hipLaunchKernelGGL(prep_kernel, dim3(76), dim3(256), 0, stream, W1L, W1V, W2V, ws);
    hipLaunchKernelGGL(lnn_kernel, dim3(32768/SMP), dim3(NT), 0, stream,
        o, a, b1L, W2L, b2L, W3L, b3L, b1V, W2V, b2V, W3V,
        ws, ws + 1536, ws + 3072, outp);
}

// Round 2
// 622.453 us; speedup vs baseline: 1.6071x; 1.6071x over previous
//
#include <hip/hip_runtime.h>

#define SMP 64      // samples per block
#define NW 8        // waves per block
#define NT (NW*64)

constexpr float DTc  = 0.02f;
constexpr float ADc  = (2.0f/3.0f)*0.02f;   // alpha*DT
constexpr float EPSc = 1e-6f;

// S (per-sample small state) field offsets, stride 117 (odd -> conflict-free)
#define FQ   0
#define FQD  6
#define FT   12
#define FL   24   // 21 tril entries of L (also y accumulator, init = b3L)
#define FM   45   // 36 full symmetric M
#define FDV  81
#define FC1  87
#define FC2  93
#define FKQ  99   // qddot of stage 1 (k1)
#define FGT  105  // 12 V-grad wrt trig feats (atomic)
#define SSTR 117

#define HS 129    // odd stride for 128-vectors

__device__ __forceinline__ float softplusf(float z) {
    return fmaxf(z, 0.0f) + __logf(1.0f + __expf(-fabsf(z)));
}
__device__ __forceinline__ float sigmoidf_(float z) {
    float t = __expf(-fabsf(z));
    float r = 1.0f / (1.0f + t);
    return z >= 0.0f ? r : t * r;
}

__global__ void prep_kernel(const float* __restrict__ W1L, const float* __restrict__ W1V,
                            const float* __restrict__ W2V, float* __restrict__ ws) {
    int idx = blockIdx.x*256 + threadIdx.x;
    if (idx < 1536) {                       // W1LT[n*12+d] = W1L[d*128+n]
        int n = idx / 12, d = idx % 12;
        ws[idx] = W1L[d*128 + n];
    } else if (idx < 3072) {                // W1VT[m*12+d] = W1V[d*128+m]
        int j = idx - 1536;
        int m = j / 12, d = j % 12;
        ws[idx] = W1V[d*128 + m];
    } else if (idx < 19456) {               // W2VT[n*128+m] = W2V[m*128+n]
        int j = idx - 3072;
        int n = j / 128, m = j % 128;
        ws[idx] = W2V[m*128 + n];
    }
}

__launch_bounds__(NT)
__global__ void lnn_kernel(
    const float* __restrict__ o,   const float* __restrict__ aIn,
    const float* __restrict__ b1L, const float* __restrict__ W2L,
    const float* __restrict__ b2L, const float* __restrict__ W3L,
    const float* __restrict__ b3L,
    const float* __restrict__ b1V, const float* __restrict__ W2V,
    const float* __restrict__ b2V, const float* __restrict__ W3V,
    const float* __restrict__ W1LT, const float* __restrict__ W1VT,
    const float* __restrict__ W2VT,
    float* __restrict__ out)
{
    __shared__ float H1[SMP*HS];   // P1: softplus(z1L); after P3: sigmoid(z1L)
    __shared__ float H2[SMP*HS];   // P0: softplus(z1V); P2: softplus(z2L); after P3: sigmoid(z2L)
    __shared__ float GH[SMP*HS];   // g2h = sigmoid(z2v)*W3V  (V backward seed)
    __shared__ float S[SMP*SSTR];

    const int tid  = threadIdx.x;
    const int lane = tid & 63;
    const int wv   = __builtin_amdgcn_readfirstlane(tid >> 6);
    const int gs   = blockIdx.x * SMP + lane;     // global sample of this lane
    float* Sl = &S[lane*SSTR];
    float* Hrow1 = &H1[lane*HS];
    float* Hrow2 = &H2[lane*HS];
    float* HrowG = &GH[lane*HS];

    constexpr int TRW[21] = {0,1,1,2,2,2,3,3,3,3,4,4,4,4,4,5,5,5,5,5,5};
    constexpr int TCW[21] = {0,0,1,0,1,2,0,1,2,3,0,1,2,3,4,0,1,2,3,4,5};

    for (int stage = 0; stage < 2; ++stage) {
        // ---------------- P0: init + trig + V layer-1 (h1v -> H2) ----------------
        float qv[6];
        if (stage == 0) {
            #pragma unroll
            for (int i = 0; i < 6; ++i) qv[i] = o[gs*18+i];
            if (wv == 0) {
                #pragma unroll
                for (int i = 0; i < 6; ++i) { Sl[FQ+i] = qv[i]; Sl[FQD+i] = o[gs*18+6+i]; }
            }
        } else {
            #pragma unroll
            for (int i = 0; i < 6; ++i) qv[i] = Sl[FQ+i];   // visible via end-of-stage barrier
        }
        float tt[12];
        #pragma unroll
        for (int i = 0; i < 6; ++i) { tt[2*i] = cosf(qv[i]); tt[2*i+1] = sinf(qv[i]); }
        if (wv == 0) {
            #pragma unroll
            for (int d = 0; d < 12; ++d) Sl[FT+d] = tt[d];
        } else if (wv == 1) {
            #pragma unroll
            for (int k = 0; k < 21; ++k) Sl[FL+k] = b3L[k];
        } else if (wv == 2) {
            #pragma unroll
            for (int i = 0; i < 6; ++i) { Sl[FC1+i] = 0.0f; Sl[FC2+i] = 0.0f; }
        } else if (wv == 3) {
            #pragma unroll
            for (int d = 0; d < 12; ++d) Sl[FGT+d] = 0.0f;
        }
        // V layer-1, own 16-row slice (computed ONCE, shared via H2)
        {
            const int m0 = __builtin_amdgcn_readfirstlane(wv * 16);
            #pragma unroll
            for (int j = 0; j < 16; ++j) {
                int m = m0 + j;
                const float4* w4 = (const float4*)&W1VT[m*12];
                float4 wa = w4[0], wb = w4[1], wc = w4[2];
                float z = b1V[m];
                z += tt[0]*wa.x + tt[1]*wa.y + tt[2]*wa.z + tt[3]*wa.w;
                z += tt[4]*wb.x + tt[5]*wb.y + tt[6]*wb.z + tt[7]*wb.w;
                z += tt[8]*wc.x + tt[9]*wc.y + tt[10]*wc.z + tt[11]*wc.w;
                Hrow2[m] = softplusf(z);
            }
        }
        __syncthreads();

        // ---------------- P1: L layer-1 (h1 -> H1) + V layer-2 (reads H2) -> GH ----------------
        {
            const int n0 = __builtin_amdgcn_readfirstlane(wv * 16);
            #pragma unroll
            for (int j = 0; j < 16; ++j) {
                int n = n0 + j;
                const float4* w4 = (const float4*)&W1LT[n*12];
                float4 wa = w4[0], wb = w4[1], wc = w4[2];
                float z = b1L[n];
                z += tt[0]*wa.x + tt[1]*wa.y + tt[2]*wa.z + tt[3]*wa.w;
                z += tt[4]*wb.x + tt[5]*wb.y + tt[6]*wb.z + tt[7]*wb.w;
                z += tt[8]*wc.x + tt[9]*wc.y + tt[10]*wc.z + tt[11]*wc.w;
                Hrow1[n] = softplusf(z);
            }
            float acc[16];
            #pragma unroll
            for (int j = 0; j < 16; ++j) acc[j] = b2V[n0+j];
            for (int m8 = 0; m8 < 128; m8 += 8) {
                float hr[8];
                #pragma unroll
                for (int t = 0; t < 8; ++t) hr[t] = Hrow2[m8+t];
                #pragma unroll
                for (int t = 0; t < 8; ++t) {
                    const float4* w4 = (const float4*)&W2V[(m8+t)*128 + n0];
                    #pragma unroll
                    for (int g = 0; g < 4; ++g) {
                        float4 w = w4[g];
                        acc[4*g+0] += hr[t]*w.x; acc[4*g+1] += hr[t]*w.y;
                        acc[4*g+2] += hr[t]*w.z; acc[4*g+3] += hr[t]*w.w;
                    }
                }
            }
            #pragma unroll
            for (int j = 0; j < 16; ++j) {
                int n = n0 + j;
                HrowG[n] = sigmoidf_(acc[j]) * W3V[n];
            }
        }
        __syncthreads();

        // ---------------- P2: L layer-2 (reads H1, writes H2) + V backward (reads GH) ----------------
        {
            const int n0 = __builtin_amdgcn_readfirstlane(wv * 16);
            // own-slice sigmoid(z1v) from stored h1v, BEFORE overwriting H2
            float sig1v[16];
            #pragma unroll
            for (int i = 0; i < 16; ++i) sig1v[i] = 1.0f - __expf(-Hrow2[n0+i]);

            float acc[16];
            #pragma unroll
            for (int j = 0; j < 16; ++j) acc[j] = b2L[n0+j];
            for (int m8 = 0; m8 < 128; m8 += 8) {
                float hr[8];
                #pragma unroll
                for (int t = 0; t < 8; ++t) hr[t] = Hrow1[m8+t];
                #pragma unroll
                for (int t = 0; t < 8; ++t) {
                    const float4* w4 = (const float4*)&W2L[(m8+t)*128 + n0];
                    #pragma unroll
                    for (int g = 0; g < 4; ++g) {
                        float4 w = w4[g];
                        acc[4*g+0] += hr[t]*w.x; acc[4*g+1] += hr[t]*w.y;
                        acc[4*g+2] += hr[t]*w.z; acc[4*g+3] += hr[t]*w.w;
                    }
                }
            }
            float yp[21];
            #pragma unroll
            for (int k = 0; k < 21; ++k) yp[k] = 0.0f;
            #pragma unroll
            for (int j = 0; j < 16; ++j) {
                int n = n0 + j;
                float h2 = softplusf(acc[j]);
                Hrow2[n] = h2;
                #pragma unroll
                for (int k = 0; k < 21; ++k) yp[k] += h2 * W3L[n*21 + k];
            }
            #pragma unroll
            for (int k = 0; k < 21; ++k) atomicAdd(&Sl[FL+k], yp[k]);

            // V backward: g1 = W2V . g2h (own m-slice), fold to gt
            float ga[16];
            #pragma unroll
            for (int i = 0; i < 16; ++i) ga[i] = 0.0f;
            for (int n8 = 0; n8 < 128; n8 += 8) {
                float gr[8];
                #pragma unroll
                for (int t = 0; t < 8; ++t) gr[t] = HrowG[n8+t];
                #pragma unroll
                for (int t = 0; t < 8; ++t) {
                    const float4* w4 = (const float4*)&W2VT[(n8+t)*128 + n0];
                    #pragma unroll
                    for (int g = 0; g < 4; ++g) {
                        float4 w = w4[g];
                        ga[4*g+0] += gr[t]*w.x; ga[4*g+1] += gr[t]*w.y;
                        ga[4*g+2] += gr[t]*w.z; ga[4*g+3] += gr[t]*w.w;
                    }
                }
            }
            float gtp[12];
            #pragma unroll
            for (int d = 0; d < 12; ++d) gtp[d] = 0.0f;
            #pragma unroll
            for (int i = 0; i < 16; ++i) {
                int m = n0 + i;
                float g1h = ga[i] * sig1v[i];
                const float4* w4 = (const float4*)&W1VT[m*12];
                float4 wa = w4[0], wb = w4[1], wc = w4[2];
                gtp[0] += g1h*wa.x; gtp[1] += g1h*wa.y; gtp[2]  += g1h*wa.z; gtp[3]  += g1h*wa.w;
                gtp[4] += g1h*wb.x; gtp[5] += g1h*wb.y; gtp[6]  += g1h*wb.z; gtp[7]  += g1h*wb.w;
                gtp[8] += g1h*wc.x; gtp[9] += g1h*wc.y; gtp[10] += g1h*wc.z; gtp[11] += g1h*wc.w;
            }
            #pragma unroll
            for (int d = 0; d < 12; ++d) atomicAdd(&Sl[FGT+d], gtp[d]);
        }
        __syncthreads();

        // ---------------- P3: M = L L^T + eps I ; dV/dq ; H1,H2 -> sigmoid in place ----------------
        if (wv < 6) {
            int i = wv;
            for (int j = 0; j < 6; ++j) {
                float s = 0.0f;
                int mn = (i < j) ? i : j;
                for (int k = 0; k <= mn; ++k)
                    s += Sl[FL + (i*(i+1))/2 + k] * Sl[FL + (j*(j+1))/2 + k];
                if (i == j) s += EPSc;
                Sl[FM + i*6 + j] = s;
            }
        } else if (wv == 6) {
            #pragma unroll
            for (int i = 0; i < 6; ++i)
                Sl[FDV+i] = -tt[2*i+1]*Sl[FGT+2*i] + tt[2*i]*Sl[FGT+2*i+1];
        }
        {
            const int n0 = __builtin_amdgcn_readfirstlane(wv * 16);
            float v1[16], v2[16];
            #pragma unroll
            for (int i = 0; i < 16; ++i) { v1[i] = Hrow1[n0+i]; v2[i] = Hrow2[n0+i]; }
            #pragma unroll
            for (int i = 0; i < 16; ++i) {
                Hrow1[n0+i] = 1.0f - __expf(-v1[i]);
                Hrow2[n0+i] = 1.0f - __expf(-v2[i]);
            }
        }
        __syncthreads();

        // ---------------- P4: 24 JVP quarter-units (dir, m-half, n-half), 3 per wave ----------------
        {
            float qd[6], u6[6], p6[6], r6[6];
            #pragma unroll
            for (int i = 0; i < 6; ++i) qd[i] = Sl[FQD+i];
            #pragma unroll
            for (int i = 0; i < 6; ++i) {
                float s = 0.0f;
                #pragma unroll
                for (int j = 0; j < 6; ++j) s += Sl[FM+i*6+j]*qd[j];
                u6[i] = s;                                  // u = M qd
            }
            #pragma unroll
            for (int i = 0; i < 6; ++i) { p6[i] = 0.0f; r6[i] = 0.0f; }
            #pragma unroll
            for (int t = 0; t < 21; ++t) {
                float Lv = Sl[FL+t];
                p6[TCW[t]] += Lv * qd[TRW[t]];              // p = L^T qd
                r6[TCW[t]] += Lv * u6[TRW[t]];              // r = L^T u
            }

            for (int uu = wv; uu < 24; uu += NW) {
                const int d     = __builtin_amdgcn_readfirstlane(uu >> 2);
                const int mbase = __builtin_amdgcn_readfirstlane(((uu >> 1) & 1) * 64);
                const int nbase = __builtin_amdgcn_readfirstlane((uu & 1) * 64);
                float tc = Sl[FT+2*d], ts = Sl[FT+2*d+1];
                float acc[64];
                #pragma unroll
                for (int n = 0; n < 64; ++n) acc[n] = 0.0f;
                for (int m8 = 0; m8 < 64; m8 += 8) {
                    float s1r[8];
                    #pragma unroll
                    for (int t = 0; t < 8; ++t) s1r[t] = Hrow1[mbase + m8 + t];
                    #pragma unroll
                    for (int t = 0; t < 8; ++t) {
                        int mm = mbase + m8 + t;
                        float u1 = tc*W1LT[mm*12 + 2*d+1] - ts*W1LT[mm*12 + 2*d];
                        float dm = s1r[t]*u1;
                        const float4* w4 = (const float4*)&W2L[mm*128 + nbase];
                        #pragma unroll
                        for (int g = 0; g < 16; ++g) {
                            float4 w = w4[g];
                            acc[4*g+0] += dm*w.x; acc[4*g+1] += dm*w.y;
                            acc[4*g+2] += dm*w.z; acc[4*g+3] += dm*w.w;
                        }
                    }
                }
                float dy[21];
                #pragma unroll
                for (int k = 0; k < 21; ++k) dy[k] = 0.0f;
                for (int n4 = 0; n4 < 64; n4 += 4) {
                    float s2r[4];
                    #pragma unroll
                    for (int t = 0; t < 4; ++t) s2r[t] = Hrow2[nbase + n4 + t];
                    #pragma unroll
                    for (int t = 0; t < 4; ++t) {
                        int nn = nbase + n4 + t;
                        float d2 = s2r[t] * acc[n4+t];
                        const float* wr = &W3L[nn*21];
                        #pragma unroll
                        for (int k = 0; k < 21; ++k) dy[k] += d2 * wr[k];
                    }
                }
                float a1[6],a2[6],a3[6],a4[6];
                #pragma unroll
                for (int i = 0; i < 6; ++i) { a1[i]=0.f; a2[i]=0.f; a3[i]=0.f; a4[i]=0.f; }
                #pragma unroll
                for (int t = 0; t < 21; ++t) {
                    float dv = dy[t];
                    a1[TRW[t]] += dv * p6[TCW[t]];          // dL . p
                    a2[TCW[t]] += dv * qd[TRW[t]];          // dL^T qd
                    a3[TRW[t]] += dv * r6[TCW[t]];          // dL . r
                    a4[TCW[t]] += dv * u6[TRW[t]];          // dL^T u
                }
                float w6[6], v6[6];
                #pragma unroll
                for (int i = 0; i < 6; ++i) { w6[i] = a1[i]; v6[i] = a3[i]; }
                #pragma unroll
                for (int t = 0; t < 21; ++t) {
                    float Lv = Sl[FL+t];
                    w6[TRW[t]] += Lv * a2[TCW[t]];          // w = dM qd
                    v6[TRW[t]] += Lv * a4[TCW[t]];          // v = dM u
                }
                float qdd = Sl[FQD + d];
                float uw = 0.0f;
                #pragma unroll
                for (int i = 0; i < 6; ++i) {
                    float mw = 0.0f;
                    #pragma unroll
                    for (int j = 0; j < 6; ++j) mw += Sl[FM+i*6+j]*w6[j];
                    atomicAdd(&Sl[FC1+i], qdd*(v6[i]+mw));  // c1 += qd_d * S_d qd
                    uw += u6[i]*w6[i];
                }
                atomicAdd(&Sl[FC2+d], 2.0f*uw);             // c2_d = qd^T S_d qd
            }
        }
        __syncthreads();

        // ---------------- P5: epilogue (wave 0): c, rhs, inv(tril(M)), qddot, RK update ----------------
        if (wv == 0) {
            float rhs[6];
            #pragma unroll
            for (int i = 0; i < 6; ++i) {
                float c = Sl[FC1+i] - 0.5f*Sl[FC2+i];
                rhs[i] = aIn[gs*6+i] - c - Sl[FDV+i];
            }
            float Mm[36];
            #pragma unroll
            for (int i = 0; i < 36; ++i) Mm[i] = Sl[FM+i];
            float Li[21];
            #pragma unroll
            for (int j = 0; j < 6; ++j) {
                float x[6];
                x[j] = 1.0f / Mm[j*6+j];
                #pragma unroll
                for (int i2 = j+1; i2 < 6; ++i2) {
                    float s = 0.0f;
                    #pragma unroll
                    for (int k = j; k < i2; ++k) s += Mm[i2*6+k]*x[k];
                    x[i2] = -s / Mm[i2*6+i2];
                }
                #pragma unroll
                for (int i2 = j; i2 < 6; ++i2) Li[(i2*(i2+1))/2 + j] = x[i2];
            }
            float y1[6];
            #pragma unroll
            for (int i = 0; i < 6; ++i) {
                float s = 0.0f;
                #pragma unroll
                for (int j = 0; j <= i; ++j) s += Li[(i*(i+1))/2+j]*rhs[j];
                y1[i] = s;
            }
            float qdd2[6];
            #pragma unroll
            for (int i = 0; i < 6; ++i) {
                float s = 0.0f;
                #pragma unroll
                for (int k = i; k < 6; ++k) s += Li[(k*(k+1))/2+i]*y1[k];
                qdd2[i] = s;
            }
            if (stage == 0) {
                #pragma unroll
                for (int i = 0; i < 6; ++i) Sl[FKQ+i] = qdd2[i];
                #pragma unroll
                for (int i = 0; i < 6; ++i) Sl[FQ+i] += ADc*Sl[FQD+i];   // uses old qd
                #pragma unroll
                for (int i = 0; i < 6; ++i) Sl[FQD+i] += ADc*qdd2[i];
            } else {
                #pragma unroll
                for (int i = 0; i < 6; ++i) {
                    float q0 = o[gs*18+i], qd0 = o[gs*18+6+i];
                    out[gs*18+i]    = q0  + DTc*(0.25f*qd0      + 0.75f*Sl[FQD+i]);
                    out[gs*18+6+i]  = qd0 + DTc*(0.25f*Sl[FKQ+i] + 0.75f*qdd2[i]);
                    out[gs*18+12+i] = o[gs*18+12+i];
                }
            }
        }
        __syncthreads();
    }
}

extern "C" void kernel_launch(void* const* d_in, const int* in_sizes, int n_in,
                              void* d_out, int out_size, void* d_ws, size_t ws_size,
                              hipStream_t stream) {
    const float* o   = (const float*)d_in[0];
    const float* a   = (const float*)d_in[1];
    const float* W1L = (const float*)d_in[2];
    const float* b1L = (const float*)d_in[3];
    const float* W2L = (const float*)d_in[4];
    const float* b2L = (const float*)d_in[5];
    const float* W3L = (const float*)d_in[6];
    const float* b3L = (const float*)d_in[7];
    const float* W1V = (const float*)d_in[8];
    const float* b1V = (const float*)d_in[9];
    const float* W2V = (const float*)d_in[10];
    const float* b2V = (const float*)d_in[11];
    const float* W3V = (const float*)d_in[12];
    float* ws   = (float*)d_ws;
    float* outp = (float*)d_out;

    hipLaunchKernelGGL(prep_kernel, dim3(76), dim3(256), 0, stream, W1L, W1V, W2V, ws);
    hipLaunchKernelGGL(lnn_kernel, dim3(32768/SMP), dim3(NT), 0, stream,
        o, a, b1L, W2L, b2L, W3L, b3L, b1V, W2V, b2V, W3V,
        ws, ws + 1536, ws + 3072, outp);
}

// Round 3
// 577.036 us; speedup vs baseline: 1.7336x; 1.0787x over previous
//
#include <hip/hip_runtime.h>

#define SMP 64      // samples per block
#define NW 8        // waves per block
#define NT (NW*64)

constexpr float DTc  = 0.02f;
constexpr float ADc  = (2.0f/3.0f)*0.02f;   // alpha*DT
constexpr float EPSc = 1e-6f;

// S (per-sample small state) field offsets, stride 117 (odd -> conflict-free)
#define FQ   0
#define FQD  6
#define FT   12
#define FL   24   // 21 tril entries of L (also y accumulator, init = b3L)
#define FM   45   // 36 full symmetric M
#define FDV  81
#define FC1  87
#define FC2  93
#define FKQ  99   // qddot of stage 1 (k1)
#define FGT  105  // 12 V-grad wrt trig feats (atomic)
#define SSTR 117

#define HS 129    // odd stride for 128-vectors

__device__ __forceinline__ float softplusf(float z) {
    return fmaxf(z, 0.0f) + __logf(1.0f + __expf(-fabsf(z)));
}
__device__ __forceinline__ float sigmoidf_(float z) {
    float t = __expf(-fabsf(z));
    float r = 1.0f / (1.0f + t);
    return z >= 0.0f ? r : t * r;
}

__global__ void prep_kernel(const float* __restrict__ W1L, const float* __restrict__ W1V,
                            const float* __restrict__ W2V, float* __restrict__ ws) {
    int idx = blockIdx.x*256 + threadIdx.x;
    if (idx < 1536) {                       // W1LT[n*12+d] = W1L[d*128+n]
        int n = idx / 12, d = idx % 12;
        ws[idx] = W1L[d*128 + n];
    } else if (idx < 3072) {                // W1VT[m*12+d] = W1V[d*128+m]
        int j = idx - 1536;
        int m = j / 12, d = j % 12;
        ws[idx] = W1V[d*128 + m];
    } else if (idx < 19456) {               // W2VT[n*128+m] = W2V[m*128+n]
        int j = idx - 3072;
        int n = j / 128, m = j % 128;
        ws[idx] = W2V[m*128 + n];
    }
}

__launch_bounds__(NT, 2)
__global__ void lnn_kernel(
    const float* __restrict__ o,   const float* __restrict__ aIn,
    const float* __restrict__ b1L, const float* __restrict__ W2L,
    const float* __restrict__ b2L, const float* __restrict__ W3L,
    const float* __restrict__ b3L,
    const float* __restrict__ b1V, const float* __restrict__ W2V,
    const float* __restrict__ b2V, const float* __restrict__ W3V,
    const float* __restrict__ W1LT, const float* __restrict__ W1VT,
    const float* __restrict__ W2VT,
    float* __restrict__ out)
{
    __shared__ float H1[SMP*HS];   // P1: softplus(z1L); after P3: sigmoid(z1L)
    __shared__ float H2[SMP*HS];   // P0: softplus(z1V); P2: softplus(z2L); after P3: sigmoid(z2L)
    __shared__ float GH[SMP*HS];   // g2h = sigmoid(z2v)*W3V  (V backward seed)
    __shared__ float S[SMP*SSTR];

    const int tid  = threadIdx.x;
    const int lane = tid & 63;
    const int wv   = __builtin_amdgcn_readfirstlane(tid >> 6);
    const int gs   = blockIdx.x * SMP + lane;     // global sample of this lane
    float* Sl = &S[lane*SSTR];
    float* Hrow1 = &H1[lane*HS];
    float* Hrow2 = &H2[lane*HS];
    float* HrowG = &GH[lane*HS];

    constexpr int TRW[21] = {0,1,1,2,2,2,3,3,3,3,4,4,4,4,4,5,5,5,5,5,5};
    constexpr int TCW[21] = {0,0,1,0,1,2,0,1,2,3,0,1,2,3,4,0,1,2,3,4,5};

    for (int stage = 0; stage < 2; ++stage) {
        // ---------------- P0: init + trig + V layer-1 (h1v -> H2) ----------------
        float qv[6];
        if (stage == 0) {
            #pragma unroll
            for (int i = 0; i < 6; ++i) qv[i] = o[gs*18+i];
            if (wv == 0) {
                #pragma unroll
                for (int i = 0; i < 6; ++i) { Sl[FQ+i] = qv[i]; Sl[FQD+i] = o[gs*18+6+i]; }
            }
        } else {
            #pragma unroll
            for (int i = 0; i < 6; ++i) qv[i] = Sl[FQ+i];   // visible via end-of-stage barrier
        }
        float tt[12];
        #pragma unroll
        for (int i = 0; i < 6; ++i) { tt[2*i] = cosf(qv[i]); tt[2*i+1] = sinf(qv[i]); }
        if (wv == 0) {
            #pragma unroll
            for (int d = 0; d < 12; ++d) Sl[FT+d] = tt[d];
        } else if (wv == 1) {
            #pragma unroll
            for (int k = 0; k < 21; ++k) Sl[FL+k] = b3L[k];
        } else if (wv == 2) {
            #pragma unroll
            for (int i = 0; i < 6; ++i) { Sl[FC1+i] = 0.0f; Sl[FC2+i] = 0.0f; }
        } else if (wv == 3) {
            #pragma unroll
            for (int d = 0; d < 12; ++d) Sl[FGT+d] = 0.0f;
        }
        // V layer-1, own 16-row slice (computed ONCE, shared via H2)
        {
            const int m0 = __builtin_amdgcn_readfirstlane(wv * 16);
            #pragma unroll
            for (int j = 0; j < 16; ++j) {
                int m = m0 + j;
                const float4* w4 = (const float4*)&W1VT[m*12];
                float4 wa = w4[0], wb = w4[1], wc = w4[2];
                float z = b1V[m];
                z += tt[0]*wa.x + tt[1]*wa.y + tt[2]*wa.z + tt[3]*wa.w;
                z += tt[4]*wb.x + tt[5]*wb.y + tt[6]*wb.z + tt[7]*wb.w;
                z += tt[8]*wc.x + tt[9]*wc.y + tt[10]*wc.z + tt[11]*wc.w;
                Hrow2[m] = softplusf(z);
            }
        }
        __syncthreads();

        // ---------------- P1: L layer-1 (h1 -> H1) + V layer-2 (reads H2) -> GH ----------------
        {
            const int n0 = __builtin_amdgcn_readfirstlane(wv * 16);
            #pragma unroll
            for (int j = 0; j < 16; ++j) {
                int n = n0 + j;
                const float4* w4 = (const float4*)&W1LT[n*12];
                float4 wa = w4[0], wb = w4[1], wc = w4[2];
                float z = b1L[n];
                z += tt[0]*wa.x + tt[1]*wa.y + tt[2]*wa.z + tt[3]*wa.w;
                z += tt[4]*wb.x + tt[5]*wb.y + tt[6]*wb.z + tt[7]*wb.w;
                z += tt[8]*wc.x + tt[9]*wc.y + tt[10]*wc.z + tt[11]*wc.w;
                Hrow1[n] = softplusf(z);
            }
            float acc[16];
            #pragma unroll
            for (int j = 0; j < 16; ++j) acc[j] = b2V[n0+j];
            for (int m8 = 0; m8 < 128; m8 += 8) {
                float hr[8];
                #pragma unroll
                for (int t = 0; t < 8; ++t) hr[t] = Hrow2[m8+t];
                #pragma unroll
                for (int t = 0; t < 8; ++t) {
                    const float4* w4 = (const float4*)&W2V[(m8+t)*128 + n0];
                    #pragma unroll
                    for (int g = 0; g < 4; ++g) {
                        float4 w = w4[g];
                        acc[4*g+0] += hr[t]*w.x; acc[4*g+1] += hr[t]*w.y;
                        acc[4*g+2] += hr[t]*w.z; acc[4*g+3] += hr[t]*w.w;
                    }
                }
            }
            #pragma unroll
            for (int j = 0; j < 16; ++j) {
                int n = n0 + j;
                HrowG[n] = sigmoidf_(acc[j]) * W3V[n];
            }
        }
        __syncthreads();

        // ---------------- P2: fused L layer-2 (H1 -> H2) + V backward (GH -> gt) ----------------
        {
            const int n0 = __builtin_amdgcn_readfirstlane(wv * 16);
            // own-slice sigmoid(z1v) from stored h1v, BEFORE overwriting H2
            float sig1v[16];
            #pragma unroll
            for (int i = 0; i < 16; ++i) sig1v[i] = 1.0f - __expf(-Hrow2[n0+i]);

            float acc[16], ga[16];
            #pragma unroll
            for (int j = 0; j < 16; ++j) { acc[j] = b2L[n0+j]; ga[j] = 0.0f; }
            for (int m8 = 0; m8 < 128; m8 += 8) {
                float hr[8], gr[8];
                #pragma unroll
                for (int t = 0; t < 8; ++t) { hr[t] = Hrow1[m8+t]; gr[t] = HrowG[m8+t]; }
                #pragma unroll
                for (int t = 0; t < 8; ++t) {
                    const float4* w4 = (const float4*)&W2L[(m8+t)*128 + n0];
                    const float4* v4 = (const float4*)&W2VT[(m8+t)*128 + n0];
                    #pragma unroll
                    for (int g = 0; g < 4; ++g) {
                        float4 w = w4[g];
                        acc[4*g+0] += hr[t]*w.x; acc[4*g+1] += hr[t]*w.y;
                        acc[4*g+2] += hr[t]*w.z; acc[4*g+3] += hr[t]*w.w;
                        float4 v = v4[g];
                        ga[4*g+0] += gr[t]*v.x; ga[4*g+1] += gr[t]*v.y;
                        ga[4*g+2] += gr[t]*v.z; ga[4*g+3] += gr[t]*v.w;
                    }
                }
            }
            float yp[21];
            #pragma unroll
            for (int k = 0; k < 21; ++k) yp[k] = 0.0f;
            #pragma unroll
            for (int j = 0; j < 16; ++j) {
                int n = n0 + j;
                float h2 = softplusf(acc[j]);
                Hrow2[n] = h2;
                #pragma unroll
                for (int k = 0; k < 21; ++k) yp[k] += h2 * W3L[n*21 + k];
            }
            #pragma unroll
            for (int k = 0; k < 21; ++k) atomicAdd(&Sl[FL+k], yp[k]);

            float gtp[12];
            #pragma unroll
            for (int d = 0; d < 12; ++d) gtp[d] = 0.0f;
            #pragma unroll
            for (int i = 0; i < 16; ++i) {
                int m = n0 + i;
                float g1h = ga[i] * sig1v[i];
                const float4* w4 = (const float4*)&W1VT[m*12];
                float4 wa = w4[0], wb = w4[1], wc = w4[2];
                gtp[0] += g1h*wa.x; gtp[1] += g1h*wa.y; gtp[2]  += g1h*wa.z; gtp[3]  += g1h*wa.w;
                gtp[4] += g1h*wb.x; gtp[5] += g1h*wb.y; gtp[6]  += g1h*wb.z; gtp[7]  += g1h*wb.w;
                gtp[8] += g1h*wc.x; gtp[9] += g1h*wc.y; gtp[10] += g1h*wc.z; gtp[11] += g1h*wc.w;
            }
            #pragma unroll
            for (int d = 0; d < 12; ++d) atomicAdd(&Sl[FGT+d], gtp[d]);
        }
        __syncthreads();

        // ---------------- P3: M = L L^T + eps I ; dV/dq ; H1,H2 -> sigmoid in place ----------------
        if (wv < 6) {
            int i = wv;
            for (int j = 0; j < 6; ++j) {
                float s = 0.0f;
                int mn = (i < j) ? i : j;
                for (int k = 0; k <= mn; ++k)
                    s += Sl[FL + (i*(i+1))/2 + k] * Sl[FL + (j*(j+1))/2 + k];
                if (i == j) s += EPSc;
                Sl[FM + i*6 + j] = s;
            }
        } else if (wv == 6) {
            #pragma unroll
            for (int i = 0; i < 6; ++i)
                Sl[FDV+i] = -tt[2*i+1]*Sl[FGT+2*i] + tt[2*i]*Sl[FGT+2*i+1];
        }
        {
            const int n0 = __builtin_amdgcn_readfirstlane(wv * 16);
            float v1[16], v2[16];
            #pragma unroll
            for (int i = 0; i < 16; ++i) { v1[i] = Hrow1[n0+i]; v2[i] = Hrow2[n0+i]; }
            #pragma unroll
            for (int i = 0; i < 16; ++i) {
                Hrow1[n0+i] = 1.0f - __expf(-v1[i]);
                Hrow2[n0+i] = 1.0f - __expf(-v2[i]);
            }
        }
        __syncthreads();

        // ---------------- P4: all-6-direction JVP, one pass over W2L; 16 cols per wave --------
        {
            float qd[6], u6[6], p6[6], r6[6];
            #pragma unroll
            for (int i = 0; i < 6; ++i) qd[i] = Sl[FQD+i];
            #pragma unroll
            for (int i = 0; i < 6; ++i) {
                float s = 0.0f;
                #pragma unroll
                for (int j = 0; j < 6; ++j) s += Sl[FM+i*6+j]*qd[j];
                u6[i] = s;                                  // u = M qd
            }
            #pragma unroll
            for (int i = 0; i < 6; ++i) { p6[i] = 0.0f; r6[i] = 0.0f; }
            #pragma unroll
            for (int t = 0; t < 21; ++t) {
                float Lv = Sl[FL+t];
                p6[TCW[t]] += Lv * qd[TRW[t]];              // p = L^T qd
                r6[TCW[t]] += Lv * u6[TRW[t]];              // r = L^T u
            }

            const int n0 = __builtin_amdgcn_readfirstlane(wv * 16);

            // acc[d][j]: JVP of z2L for direction d, column n0+j. 96 VGPRs.
            float acc[96];
            #pragma unroll
            for (int i = 0; i < 96; ++i) acc[i] = 0.0f;

            for (int m2 = 0; m2 < 128; m2 += 2) {
                float s1a = Hrow1[m2];        // sigmoid(z1L), per-lane LDS
                float s1b = Hrow1[m2+1];
                #pragma unroll
                for (int half = 0; half < 2; ++half) {
                    const int mm = m2 + half;
                    const float s1 = half ? s1b : s1a;
                    const float4* w1 = (const float4*)&W1LT[mm*12];
                    float4 wa = w1[0], wb = w1[1], wc = w1[2];
                    float dm[6];
                    dm[0] = s1*(tt[0]*wa.y - tt[1]*wa.x);
                    dm[1] = s1*(tt[2]*wa.w - tt[3]*wa.z);
                    dm[2] = s1*(tt[4]*wb.y - tt[5]*wb.x);
                    dm[3] = s1*(tt[6]*wb.w - tt[7]*wb.z);
                    dm[4] = s1*(tt[8]*wc.y - tt[9]*wc.x);
                    dm[5] = s1*(tt[10]*wc.w - tt[11]*wc.z);
                    const float4* w2 = (const float4*)&W2L[mm*128 + n0];
                    #pragma unroll
                    for (int g = 0; g < 4; ++g) {
                        float4 w = w2[g];
                        #pragma unroll
                        for (int d = 0; d < 6; ++d) {
                            acc[d*16 + 4*g+0] += dm[d]*w.x;
                            acc[d*16 + 4*g+1] += dm[d]*w.y;
                            acc[d*16 + 4*g+2] += dm[d]*w.z;
                            acc[d*16 + 4*g+3] += dm[d]*w.w;
                        }
                    }
                }
            }

            float sig2s[16];
            #pragma unroll
            for (int j = 0; j < 16; ++j) sig2s[j] = Hrow2[n0+j];

            float c1loc[6], c2loc[6];
            #pragma unroll
            for (int i = 0; i < 6; ++i) { c1loc[i] = 0.0f; c2loc[i] = 0.0f; }

            #pragma unroll
            for (int d = 0; d < 6; ++d) {
                float dy[21];
                #pragma unroll
                for (int k = 0; k < 21; ++k) dy[k] = 0.0f;
                #pragma unroll
                for (int j = 0; j < 16; ++j) {
                    float d2 = sig2s[j] * acc[d*16+j];
                    const float* wr = &W3L[(n0+j)*21];
                    #pragma unroll
                    for (int k = 0; k < 21; ++k) dy[k] += d2 * wr[k];
                }
                float a1[6],a2[6],a3[6],a4[6];
                #pragma unroll
                for (int i = 0; i < 6; ++i) { a1[i]=0.f; a2[i]=0.f; a3[i]=0.f; a4[i]=0.f; }
                #pragma unroll
                for (int t = 0; t < 21; ++t) {
                    float dv = dy[t];
                    a1[TRW[t]] += dv * p6[TCW[t]];          // dL . p
                    a2[TCW[t]] += dv * qd[TRW[t]];          // dL^T qd
                    a3[TRW[t]] += dv * r6[TCW[t]];          // dL . r
                    a4[TCW[t]] += dv * u6[TRW[t]];          // dL^T u
                }
                float w6[6], v6[6];
                #pragma unroll
                for (int i = 0; i < 6; ++i) { w6[i] = a1[i]; v6[i] = a3[i]; }
                #pragma unroll
                for (int t = 0; t < 21; ++t) {
                    float Lv = Sl[FL+t];
                    w6[TRW[t]] += Lv * a2[TCW[t]];          // w = dM qd
                    v6[TRW[t]] += Lv * a4[TCW[t]];          // v = dM u
                }
                float qdd = qd[d];
                float uw = 0.0f;
                #pragma unroll
                for (int i = 0; i < 6; ++i) {
                    float mw = 0.0f;
                    #pragma unroll
                    for (int j = 0; j < 6; ++j) mw += Sl[FM+i*6+j]*w6[j];
                    c1loc[i] += qdd*(v6[i]+mw);             // c1 += qd_d * S_d qd
                    uw += u6[i]*w6[i];
                }
                c2loc[d] = 2.0f*uw;                         // c2_d partial (this wave's n-slice)
            }
            #pragma unroll
            for (int i = 0; i < 6; ++i) atomicAdd(&Sl[FC1+i], c1loc[i]);
            #pragma unroll
            for (int d = 0; d < 6; ++d) atomicAdd(&Sl[FC2+d], c2loc[d]);
        }
        __syncthreads();

        // ---------------- P5: epilogue (wave 0): c, rhs, inv(tril(M)), qddot, RK update ----------------
        if (wv == 0) {
            float rhs[6];
            #pragma unroll
            for (int i = 0; i < 6; ++i) {
                float c = Sl[FC1+i] - 0.5f*Sl[FC2+i];
                rhs[i] = aIn[gs*6+i] - c - Sl[FDV+i];
            }
            float Mm[36];
            #pragma unroll
            for (int i = 0; i < 36; ++i) Mm[i] = Sl[FM+i];
            float Li[21];
            #pragma unroll
            for (int j = 0; j < 6; ++j) {
                float x[6];
                x[j] = 1.0f / Mm[j*6+j];
                #pragma unroll
                for (int i2 = j+1; i2 < 6; ++i2) {
                    float s = 0.0f;
                    #pragma unroll
                    for (int k = j; k < i2; ++k) s += Mm[i2*6+k]*x[k];
                    x[i2] = -s / Mm[i2*6+i2];
                }
                #pragma unroll
                for (int i2 = j; i2 < 6; ++i2) Li[(i2*(i2+1))/2 + j] = x[i2];
            }
            float y1[6];
            #pragma unroll
            for (int i = 0; i < 6; ++i) {
                float s = 0.0f;
                #pragma unroll
                for (int j = 0; j <= i; ++j) s += Li[(i*(i+1))/2+j]*rhs[j];
                y1[i] = s;
            }
            float qdd2[6];
            #pragma unroll
            for (int i = 0; i < 6; ++i) {
                float s = 0.0f;
                #pragma unroll
                for (int k = i; k < 6; ++k) s += Li[(k*(k+1))/2+i]*y1[k];
                qdd2[i] = s;
            }
            if (stage == 0) {
                #pragma unroll
                for (int i = 0; i < 6; ++i) Sl[FKQ+i] = qdd2[i];
                #pragma unroll
                for (int i = 0; i < 6; ++i) Sl[FQ+i] += ADc*Sl[FQD+i];   // uses old qd
                #pragma unroll
                for (int i = 0; i < 6; ++i) Sl[FQD+i] += ADc*qdd2[i];
            } else {
                #pragma unroll
                for (int i = 0; i < 6; ++i) {
                    float q0 = o[gs*18+i], qd0 = o[gs*18+6+i];
                    out[gs*18+i]    = q0  + DTc*(0.25f*qd0      + 0.75f*Sl[FQD+i]);
                    out[gs*18+6+i]  = qd0 + DTc*(0.25f*Sl[FKQ+i] + 0.75f*qdd2[i]);
                    out[gs*18+12+i] = o[gs*18+12+i];
                }
            }
        }
        __syncthreads();
    }
}

extern "C" void kernel_launch(void* const* d_in, const int* in_sizes, int n_in,
                              void* d_out, int out_size, void* d_ws, size_t ws_size,
                              hipStream_t stream) {
    const float* o   = (const float*)d_in[0];
    const float* a   = (const float*)d_in[1];
    const float* W1L = (const float*)d_in[2];
    const float* b1L = (const float*)d_in[3];
    const float* W2L = (const float*)d_in[4];
    const float* b2L = (const float*)d_in[5];
    const float* W3L = (const float*)d_in[6];
    const float* b3L = (const float*)d_in[7];
    const float* W1V = (const float*)d_in[8];
    const float* b1V = (const float*)d_in[9];
    const float* W2V = (const float*)d_in[10];
    const float* b2V = (const float*)d_in[11];
    const float* W3V = (const float*)d_in[12];
    float* ws   = (float*)d_ws;
    float* outp = (float*)d_out;

    hipLaunchKernelGGL(prep_kernel, dim3(76), dim3(256), 0, stream, W1L, W1V, W2V, ws);
    hipLaunchKernelGGL(lnn_kernel, dim3(32768/SMP), dim3(NT), 0, stream,
        o, a, b1L, W2L, b2L, W3L, b3L, b1V, W2V, b2V, W3V,
        ws, ws + 1536, ws + 3072, outp);
}